// Round 4
// baseline (177.460 us; speedup 1.0000x reference)
//
#include <hip/hip_runtime.h>
#include <hip/hip_bf16.h>

typedef __attribute__((ext_vector_type(8))) short short8;
typedef __attribute__((ext_vector_type(4))) float f32x4;

#define N_U 8192
#define N_I 8192
#define KD  256

// global_load_lds, 16B per lane.
#define GLD16(g, l) __builtin_amdgcn_global_load_lds( \
    (const __attribute__((address_space(1))) unsigned int*)(unsigned long long)(uintptr_t)(g), \
    (__attribute__((address_space(3))) unsigned int*)(unsigned int)(uintptr_t)(l), 16, 0, 0)

static __device__ __forceinline__ unsigned short f2bf(float x) {
  unsigned u = __builtin_bit_cast(unsigned, x);
  u += 0x7fffu + ((u >> 16) & 1u);   // round-to-nearest-even
  return (unsigned short)(u >> 16);
}

static __device__ __forceinline__ void block_reduce_atomic(float v, float* dst) {
  #pragma unroll
  for (int off = 32; off > 0; off >>= 1) v += __shfl_down(v, off, 64);
  __shared__ float red[4];
  int lane = threadIdx.x & 63, wv = threadIdx.x >> 6;
  if (lane == 0) red[wv] = v;
  __syncthreads();
  if (threadIdx.x == 0) atomicAdd(dst, red[0] + red[1] + red[2] + red[3]);
}

// A = P.T (elementwise*) U  -> bf16 [N_U][KD]; also accumulates sum(U^2)+sum(P^2).
__global__ __launch_bounds__(256) void pack_a_kernel(
    const float* __restrict__ U, const float* __restrict__ P,
    unsigned short* __restrict__ Abf, float* __restrict__ regsum)
{
  __shared__ float Pt[64][65];   // +1 pad
  const int u0 = blockIdx.x * 64;
  const int k0 = blockIdx.y * 64;
  const int t = threadIdx.x;
  float ss = 0.f;
  {
    const int ul4 = (t & 15) * 4, klb = t >> 4;
    #pragma unroll
    for (int pass = 0; pass < 4; ++pass) {
      int kl = klb + pass * 16;
      float4 pv = *(const float4*)&P[(size_t)(k0 + kl) * N_U + u0 + ul4];
      Pt[kl][ul4 + 0] = pv.x; Pt[kl][ul4 + 1] = pv.y;
      Pt[kl][ul4 + 2] = pv.z; Pt[kl][ul4 + 3] = pv.w;
      ss += pv.x * pv.x + pv.y * pv.y + pv.z * pv.z + pv.w * pv.w;
    }
  }
  __syncthreads();
  {
    const int k4 = (t & 15) * 4, ulb = t >> 4;
    #pragma unroll
    for (int pass = 0; pass < 4; ++pass) {
      int ul = ulb + pass * 16;
      float4 uv = *(const float4*)&U[(size_t)(u0 + ul) * KD + k0 + k4];
      ss += uv.x * uv.x + uv.y * uv.y + uv.z * uv.z + uv.w * uv.w;
      ushort4 w;
      w.x = f2bf(uv.x * Pt[k4 + 0][ul]);
      w.y = f2bf(uv.y * Pt[k4 + 1][ul]);
      w.z = f2bf(uv.z * Pt[k4 + 2][ul]);
      w.w = f2bf(uv.w * Pt[k4 + 3][ul]);
      *(ushort4*)&Abf[(size_t)(u0 + ul) * KD + k0 + k4] = w;
    }
  }
  block_reduce_atomic(ss, regsum);
}

// V -> bf16, accumulating sum(V^2).
__global__ __launch_bounds__(256) void pack_v_kernel(
    const float* __restrict__ V, unsigned short* __restrict__ Vbf,
    float* __restrict__ regsum)
{
  size_t i = ((size_t)blockIdx.x * 256 + threadIdx.x) * 4;
  float4 v = *(const float4*)&V[i];
  float ss = v.x * v.x + v.y * v.y + v.z * v.z + v.w * v.w;
  ushort4 w;
  w.x = f2bf(v.x); w.y = f2bf(v.y); w.z = f2bf(v.z); w.w = f2bf(v.w);
  *(ushort4*)&Vbf[i] = w;
  block_reduce_atomic(ss, regsum);
}

// 128x128 output tile, BK=32, 4 waves (2x2), mfma_f32_16x16x32_bf16.
// Epilogue v2: dump acc to a pred[128][128] f32 LDS tile, then read the R
// tile COALESCED (float4, 512B contiguous per 32-lane group) and compare
// against LDS. This replaces the 64B-granule strided R reads (the suspected
// ~2.2 TB/s bottleneck) with wide streaming reads.
__global__ __launch_bounds__(256, 2) void gemm_loss_kernel(
    const float* __restrict__ R, const unsigned short* __restrict__ Abf,
    const unsigned short* __restrict__ Vbf, float* __restrict__ err_acc)
{
  __shared__ unsigned short As[128 * 32];   // 8 KB
  __shared__ unsigned short Bs[128 * 32];   // 8 KB
  __shared__ float pred[128 * 128];         // 64 KB
  const int tid = threadIdx.x;
  const int wv = tid >> 6, lane = tid & 63;
  const int brow = blockIdx.x, bcol = blockIdx.y;
  const int wr = wv >> 1, wc = wv & 1;

  f32x4 acc[4][4] = {};

  const unsigned short* Ag = Abf + (size_t)brow * 128 * KD;
  const unsigned short* Bg = Vbf + (size_t)bcol * 128 * KD;
  const int f0 = (wv * 2 + 0) * 64 + lane;   // 16B-chunk index 0..511
  const int f1 = f0 + 64;
  const int r0 = lane & 15, kc = (lane >> 4) * 8;

  for (int kt = 0; kt < KD; kt += 32) {
    __syncthreads();
    GLD16(Ag + ((f0 >> 2) * KD + kt + (f0 & 3) * 8), &As[f0 * 8]);
    GLD16(Bg + ((f0 >> 2) * KD + kt + (f0 & 3) * 8), &Bs[f0 * 8]);
    GLD16(Ag + ((f1 >> 2) * KD + kt + (f1 & 3) * 8), &As[f1 * 8]);
    GLD16(Bg + ((f1 >> 2) * KD + kt + (f1 & 3) * 8), &Bs[f1 * 8]);
    __syncthreads();
    short8 a[4], b[4];
    #pragma unroll
    for (int m = 0; m < 4; ++m)
      a[m] = *(const short8*)&As[(wr * 64 + m * 16 + r0) * 32 + kc];
    #pragma unroll
    for (int n = 0; n < 4; ++n)
      b[n] = *(const short8*)&Bs[(wc * 64 + n * 16 + r0) * 32 + kc];
    #pragma unroll
    for (int m = 0; m < 4; ++m)
      #pragma unroll
      for (int n = 0; n < 4; ++n)
        acc[m][n] = __builtin_amdgcn_mfma_f32_16x16x32_bf16(a[m], b[n], acc[m][n], 0, 0, 0);
  }

  // C/D layout (m89-verified): col = lane&15, row = (lane>>4)*4 + j
  {
    const int rloc = wr * 64 + (lane >> 4) * 4;
    const int cloc = wc * 64 + (lane & 15);
    #pragma unroll
    for (int m = 0; m < 4; ++m)
      #pragma unroll
      for (int n = 0; n < 4; ++n)
        #pragma unroll
        for (int j = 0; j < 4; ++j)
          pred[(rloc + m * 16 + j) * 128 + cloc + n * 16] = acc[m][n][j];
  }
  __syncthreads();

  // Coalesced masked-SSE: 256 threads x float4 = 8 rows (128 cols) per iter.
  float lsum = 0.f;
  const float* Rt = R + (size_t)(brow * 128) * N_I + (size_t)bcol * 128;
  const int rr = tid >> 5, cc = (tid & 31) * 4;
  #pragma unroll
  for (int i = 0; i < 16; ++i) {
    const int r = i * 8 + rr;
    float4 rv = *(const float4*)&Rt[(size_t)r * N_I + cc];
    float4 pv = *(const float4*)&pred[r * 128 + cc];
    if (rv.x != 0.f) { float d = rv.x - pv.x; lsum += d * d; }
    if (rv.y != 0.f) { float d = rv.y - pv.y; lsum += d * d; }
    if (rv.z != 0.f) { float d = rv.z - pv.z; lsum += d * d; }
    if (rv.w != 0.f) { float d = rv.w - pv.w; lsum += d * d; }
  }

  // block reduce, reusing As as scratch (free after the K-loop).
  #pragma unroll
  for (int off = 32; off > 0; off >>= 1) lsum += __shfl_down(lsum, off, 64);
  float* red = (float*)As;
  __syncthreads();
  if (lane == 0) red[wv] = lsum;
  __syncthreads();
  if (tid == 0) atomicAdd(err_acc, red[0] + red[1] + red[2] + red[3]);
}

__global__ void finalize_kernel(const float* __restrict__ ws, float* __restrict__ out) {
  // loss = err/2 + 0.1/2 * (sumU2 + sumV2 + sumP2)
  out[0] = 0.5f * ws[0] + 0.05f * ws[1];
}

extern "C" void kernel_launch(void* const* d_in, const int* in_sizes, int n_in,
                              void* d_out, int out_size, void* d_ws, size_t ws_size,
                              hipStream_t stream) {
  const float* R = (const float*)d_in[0];
  const float* U = (const float*)d_in[1];
  const float* V = (const float*)d_in[2];
  // d_in[3]=alpha, d_in[4]=Y, d_in[6]=Q: dead w.r.t. the returned value.
  const float* P = (const float*)d_in[5];

  float* ws = (float*)d_ws;                                   // [0]=err, [1]=regsum
  unsigned short* Abf = (unsigned short*)((char*)d_ws + 256); // 4 MiB
  unsigned short* Vbf = Abf + (size_t)N_U * KD;               // 4 MiB
  float* out = (float*)d_out;

  hipMemsetAsync(d_ws, 0, 256, stream);
  pack_a_kernel<<<dim3(N_U / 64, KD / 64), 256, 0, stream>>>(U, P, Abf, ws + 1);
  pack_v_kernel<<<dim3((N_I * KD) / (256 * 4)), 256, 0, stream>>>(V, Vbf, ws + 1);
  gemm_loss_kernel<<<dim3(64, 64), 256, 0, stream>>>(R, Abf, Vbf, ws + 0);
  finalize_kernel<<<1, 1, 0, stream>>>(ws, out);
}

// Round 5
// 150.757 us; speedup vs baseline: 1.1771x; 1.1771x over previous
//
#include <hip/hip_runtime.h>
#include <hip/hip_bf16.h>

typedef __attribute__((ext_vector_type(8))) short short8;
typedef __attribute__((ext_vector_type(4))) float f32x4;

#define N_U 8192
#define N_I 8192
#define KD  256

// global_load_lds, 16B per lane.
#define GLD16(g, l) __builtin_amdgcn_global_load_lds( \
    (const __attribute__((address_space(1))) unsigned int*)(unsigned long long)(uintptr_t)(g), \
    (__attribute__((address_space(3))) unsigned int*)(unsigned int)(uintptr_t)(l), 16, 0, 0)

static __device__ __forceinline__ unsigned short f2bf(float x) {
  unsigned u = __builtin_bit_cast(unsigned, x);
  u += 0x7fffu + ((u >> 16) & 1u);   // round-to-nearest-even
  return (unsigned short)(u >> 16);
}

static __device__ __forceinline__ void block_reduce_atomic(float v, float* dst) {
  #pragma unroll
  for (int off = 32; off > 0; off >>= 1) v += __shfl_down(v, off, 64);
  __shared__ float red[4];
  int lane = threadIdx.x & 63, wv = threadIdx.x >> 6;
  if (lane == 0) red[wv] = v;
  __syncthreads();
  if (threadIdx.x == 0) atomicAdd(dst, red[0] + red[1] + red[2] + red[3]);
}

// A = P.T (elementwise*) U  -> bf16 [N_U][KD]; also accumulates sum(U^2)+sum(P^2).
__global__ __launch_bounds__(256) void pack_a_kernel(
    const float* __restrict__ U, const float* __restrict__ P,
    unsigned short* __restrict__ Abf, float* __restrict__ regsum)
{
  __shared__ float Pt[64][65];   // +1 pad
  const int u0 = blockIdx.x * 64;
  const int k0 = blockIdx.y * 64;
  const int t = threadIdx.x;
  float ss = 0.f;
  {
    const int ul4 = (t & 15) * 4, klb = t >> 4;
    #pragma unroll
    for (int pass = 0; pass < 4; ++pass) {
      int kl = klb + pass * 16;
      float4 pv = *(const float4*)&P[(size_t)(k0 + kl) * N_U + u0 + ul4];
      Pt[kl][ul4 + 0] = pv.x; Pt[kl][ul4 + 1] = pv.y;
      Pt[kl][ul4 + 2] = pv.z; Pt[kl][ul4 + 3] = pv.w;
      ss += pv.x * pv.x + pv.y * pv.y + pv.z * pv.z + pv.w * pv.w;
    }
  }
  __syncthreads();
  {
    const int k4 = (t & 15) * 4, ulb = t >> 4;
    #pragma unroll
    for (int pass = 0; pass < 4; ++pass) {
      int ul = ulb + pass * 16;
      float4 uv = *(const float4*)&U[(size_t)(u0 + ul) * KD + k0 + k4];
      ss += uv.x * uv.x + uv.y * uv.y + uv.z * uv.z + uv.w * uv.w;
      ushort4 w;
      w.x = f2bf(uv.x * Pt[k4 + 0][ul]);
      w.y = f2bf(uv.y * Pt[k4 + 1][ul]);
      w.z = f2bf(uv.z * Pt[k4 + 2][ul]);
      w.w = f2bf(uv.w * Pt[k4 + 3][ul]);
      *(ushort4*)&Abf[(size_t)(u0 + ul) * KD + k0 + k4] = w;
    }
  }
  block_reduce_atomic(ss, regsum);
}

// V -> bf16, accumulating sum(V^2).
__global__ __launch_bounds__(256) void pack_v_kernel(
    const float* __restrict__ V, unsigned short* __restrict__ Vbf,
    float* __restrict__ regsum)
{
  size_t i = ((size_t)blockIdx.x * 256 + threadIdx.x) * 4;
  float4 v = *(const float4*)&V[i];
  float ss = v.x * v.x + v.y * v.y + v.z * v.z + v.w * v.w;
  ushort4 w;
  w.x = f2bf(v.x); w.y = f2bf(v.y); w.z = f2bf(v.z); w.w = f2bf(v.w);
  *(ushort4*)&Vbf[i] = w;
  block_reduce_atomic(ss, regsum);
}

// 128x128 output tile, BK=32, 4 waves (2x2), mfma_f32_16x16x32_bf16.
// Latency fix (R4 post-mortem): the 64KB R tile is prefetched into LDS via
// global_load_lds SPREAD ACROSS the 8 K-iterations (8KB/iter, issued before
// the panel loads), so the HBM R-stream overlaps the whole K-loop instead of
// being a serial, latency-exposed epilogue. Epilogue then reads R from LDS
// in the accumulator layout (no global traffic, no pred round-trip).
__global__ __launch_bounds__(256, 2) void gemm_loss_kernel(
    const float* __restrict__ R, const unsigned short* __restrict__ Abf,
    const unsigned short* __restrict__ Vbf, float* __restrict__ err_acc)
{
  __shared__ unsigned short As[128 * 32];   // 8 KB
  __shared__ unsigned short Bs[128 * 32];   // 8 KB
  __shared__ float Rs[128 * 128];           // 64 KB, row-major [128][128]
  const int tid = threadIdx.x;
  const int wv = tid >> 6, lane = tid & 63;
  const int brow = blockIdx.x, bcol = blockIdx.y;
  const int wr = wv >> 1, wc = wv & 1;

  f32x4 acc[4][4] = {};

  const unsigned short* Ag = Abf + (size_t)brow * 128 * KD;
  const unsigned short* Bg = Vbf + (size_t)bcol * 128 * KD;
  const float* Rt = R + (size_t)(brow * 128) * N_I + (size_t)bcol * 128;
  const int f0 = wv * 128 + lane;   // 16B-chunk index, covers [0,512) with f1
  const int f1 = f0 + 64;
  const int r0 = lane & 15, kc = (lane >> 4) * 8;

  #pragma unroll
  for (int it = 0; it < 8; ++it) {
    const int kt = it * 32;
    __syncthreads();
    // R prefetch first (HBM, longest latency): 16 rows = 8KB this iter.
    // chunk f: row = it*16 + (f>>5), col = (f&31)*4 floats; LDS stays linear.
    GLD16(Rt + (size_t)(it * 16 + (f0 >> 5)) * N_I + (f0 & 31) * 4, &Rs[it * 2048 + f0 * 4]);
    GLD16(Rt + (size_t)(it * 16 + (f1 >> 5)) * N_I + (f1 & 31) * 4, &Rs[it * 2048 + f1 * 4]);
    // panel staging (L2/L3-resident)
    GLD16(Ag + ((f0 >> 2) * KD + kt + (f0 & 3) * 8), &As[f0 * 8]);
    GLD16(Bg + ((f0 >> 2) * KD + kt + (f0 & 3) * 8), &Bs[f0 * 8]);
    GLD16(Ag + ((f1 >> 2) * KD + kt + (f1 & 3) * 8), &As[f1 * 8]);
    GLD16(Bg + ((f1 >> 2) * KD + kt + (f1 & 3) * 8), &Bs[f1 * 8]);
    __syncthreads();
    short8 a[4], b[4];
    #pragma unroll
    for (int m = 0; m < 4; ++m)
      a[m] = *(const short8*)&As[(wr * 64 + m * 16 + r0) * 32 + kc];
    #pragma unroll
    for (int n = 0; n < 4; ++n)
      b[n] = *(const short8*)&Bs[(wc * 64 + n * 16 + r0) * 32 + kc];
    #pragma unroll
    for (int m = 0; m < 4; ++m)
      #pragma unroll
      for (int n = 0; n < 4; ++n)
        acc[m][n] = __builtin_amdgcn_mfma_f32_16x16x32_bf16(a[m], b[n], acc[m][n], 0, 0, 0);
  }

  // Epilogue: compare acc (C/D layout: col = lane&15, row = (lane>>4)*4 + j)
  // against the LDS-resident R tile. Pure LDS + VALU.
  float lsum = 0.f;
  const int rloc = wr * 64 + (lane >> 4) * 4;
  const int cloc = wc * 64 + (lane & 15);
  #pragma unroll
  for (int m = 0; m < 4; ++m) {
    #pragma unroll
    for (int n = 0; n < 4; ++n) {
      #pragma unroll
      for (int j = 0; j < 4; ++j) {
        float rv = Rs[(rloc + m * 16 + j) * 128 + cloc + n * 16];
        if (rv != 0.f) { float d = rv - acc[m][n][j]; lsum += d * d; }
      }
    }
  }

  // block reduce, reusing As as scratch (all LDS frag reads are done).
  #pragma unroll
  for (int off = 32; off > 0; off >>= 1) lsum += __shfl_down(lsum, off, 64);
  float* red = (float*)As;
  __syncthreads();
  if (lane == 0) red[wv] = lsum;
  __syncthreads();
  if (tid == 0) atomicAdd(err_acc, red[0] + red[1] + red[2] + red[3]);
}

__global__ void finalize_kernel(const float* __restrict__ ws, float* __restrict__ out) {
  // loss = err/2 + 0.1/2 * (sumU2 + sumV2 + sumP2)
  out[0] = 0.5f * ws[0] + 0.05f * ws[1];
}

extern "C" void kernel_launch(void* const* d_in, const int* in_sizes, int n_in,
                              void* d_out, int out_size, void* d_ws, size_t ws_size,
                              hipStream_t stream) {
  const float* R = (const float*)d_in[0];
  const float* U = (const float*)d_in[1];
  const float* V = (const float*)d_in[2];
  // d_in[3]=alpha, d_in[4]=Y, d_in[6]=Q: dead w.r.t. the returned value.
  const float* P = (const float*)d_in[5];

  float* ws = (float*)d_ws;                                   // [0]=err, [1]=regsum
  unsigned short* Abf = (unsigned short*)((char*)d_ws + 256); // 4 MiB
  unsigned short* Vbf = Abf + (size_t)N_U * KD;               // 4 MiB
  float* out = (float*)d_out;

  hipMemsetAsync(d_ws, 0, 256, stream);
  pack_a_kernel<<<dim3(N_U / 64, KD / 64), 256, 0, stream>>>(U, P, Abf, ws + 1);
  pack_v_kernel<<<dim3((N_I * KD) / (256 * 4)), 256, 0, stream>>>(V, Vbf, ws + 1);
  gemm_loss_kernel<<<dim3(64, 64), 256, 0, stream>>>(R, Abf, Vbf, ws + 0);
  finalize_kernel<<<1, 1, 0, stream>>>(ws, out);
}

// Round 6
// 104.188 us; speedup vs baseline: 1.7033x; 1.4470x over previous
//
#include <hip/hip_runtime.h>
#include <hip/hip_bf16.h>

typedef __attribute__((ext_vector_type(8))) short short8;
typedef __attribute__((ext_vector_type(4))) float f32x4;

#define N_U 8192
#define N_I 8192
#define KD  256

// ws slot layout (floats): [0,4096) gemm err partials; [4096,4608) pack_a
// reg partials; [4608,6656) pack_v reg partials. Every slot is written
// unconditionally every launch (plain stores, no atomics, no memset needed).
#define ERR_SLOTS 4096
#define REGA_BASE 4096
#define REGV_BASE 4608
#define SLOTS_END 6656

// global_load_lds, 16B per lane.
#define GLD16(g, l) __builtin_amdgcn_global_load_lds( \
    (const __attribute__((address_space(1))) unsigned int*)(unsigned long long)(uintptr_t)(g), \
    (__attribute__((address_space(3))) unsigned int*)(unsigned int)(uintptr_t)(l), 16, 0, 0)

static __device__ __forceinline__ unsigned short f2bf(float x) {
  unsigned u = __builtin_bit_cast(unsigned, x);
  u += 0x7fffu + ((u >> 16) & 1u);   // round-to-nearest-even
  return (unsigned short)(u >> 16);
}

// Block reduce; thread 0 plain-stores the block's partial into its slot.
static __device__ __forceinline__ void block_reduce_store(float v, float* slot) {
  #pragma unroll
  for (int off = 32; off > 0; off >>= 1) v += __shfl_down(v, off, 64);
  __shared__ float red[4];
  int lane = threadIdx.x & 63, wv = threadIdx.x >> 6;
  if (lane == 0) red[wv] = v;
  __syncthreads();
  if (threadIdx.x == 0) *slot = red[0] + red[1] + red[2] + red[3];
}

// A = P.T (elementwise*) U  -> bf16 [N_U][KD]; partial sum(U^2)+sum(P^2) to slot.
__global__ __launch_bounds__(256) void pack_a_kernel(
    const float* __restrict__ U, const float* __restrict__ P,
    unsigned short* __restrict__ Abf, float* __restrict__ ws)
{
  __shared__ float Pt[64][65];   // +1 pad
  const int u0 = blockIdx.x * 64;
  const int k0 = blockIdx.y * 64;
  const int t = threadIdx.x;
  float ss = 0.f;
  {
    const int ul4 = (t & 15) * 4, klb = t >> 4;
    #pragma unroll
    for (int pass = 0; pass < 4; ++pass) {
      int kl = klb + pass * 16;
      float4 pv = *(const float4*)&P[(size_t)(k0 + kl) * N_U + u0 + ul4];
      Pt[kl][ul4 + 0] = pv.x; Pt[kl][ul4 + 1] = pv.y;
      Pt[kl][ul4 + 2] = pv.z; Pt[kl][ul4 + 3] = pv.w;
      ss += pv.x * pv.x + pv.y * pv.y + pv.z * pv.z + pv.w * pv.w;
    }
  }
  __syncthreads();
  {
    const int k4 = (t & 15) * 4, ulb = t >> 4;
    #pragma unroll
    for (int pass = 0; pass < 4; ++pass) {
      int ul = ulb + pass * 16;
      float4 uv = *(const float4*)&U[(size_t)(u0 + ul) * KD + k0 + k4];
      ss += uv.x * uv.x + uv.y * uv.y + uv.z * uv.z + uv.w * uv.w;
      ushort4 w;
      w.x = f2bf(uv.x * Pt[k4 + 0][ul]);
      w.y = f2bf(uv.y * Pt[k4 + 1][ul]);
      w.z = f2bf(uv.z * Pt[k4 + 2][ul]);
      w.w = f2bf(uv.w * Pt[k4 + 3][ul]);
      *(ushort4*)&Abf[(size_t)(u0 + ul) * KD + k0 + k4] = w;
    }
  }
  block_reduce_store(ss, ws + REGA_BASE + blockIdx.y * 128 + blockIdx.x);
}

// V -> bf16; partial sum(V^2) to slot.
__global__ __launch_bounds__(256) void pack_v_kernel(
    const float* __restrict__ V, unsigned short* __restrict__ Vbf,
    float* __restrict__ ws)
{
  size_t i = ((size_t)blockIdx.x * 256 + threadIdx.x) * 4;
  float4 v = *(const float4*)&V[i];
  float ss = v.x * v.x + v.y * v.y + v.z * v.z + v.w * v.w;
  ushort4 w;
  w.x = f2bf(v.x); w.y = f2bf(v.y); w.z = f2bf(v.z); w.w = f2bf(v.w);
  *(ushort4*)&Vbf[i] = w;
  block_reduce_store(ss, ws + REGV_BASE + blockIdx.x);
}

// 128x128 tile, BK=32, 4 waves (2x2), mfma_f32_16x16x32_bf16 with SWAPPED
// operands: acc[m][n] = mfma(b[n], a[m], .). Output mapping then is
//   pred_row = brow*128 + wr*64 + m*16 + (lane&15)
//   pred_col = bcol*128 + wc*64 + n*16 + (lane>>4)*4 + j
// so each lane's 4 acc values sit on 4 CONSECUTIVE R columns -> the masked-SSE
// epilogue is 16 independent float4 loads per thread (good MLP), same 64B
// DRAM segments as before but 4x fewer instructions. Partial -> slot store
// (no same-address atomics anywhere).
__global__ __launch_bounds__(256) void gemm_loss_kernel(
    const float* __restrict__ R, const unsigned short* __restrict__ Abf,
    const unsigned short* __restrict__ Vbf, float* __restrict__ ws)
{
  __shared__ unsigned short As[128 * 32];   // 8 KB
  __shared__ unsigned short Bs[128 * 32];   // 8 KB
  const int tid = threadIdx.x;
  const int wv = tid >> 6, lane = tid & 63;
  const int brow = blockIdx.x, bcol = blockIdx.y;
  const int wr = wv >> 1, wc = wv & 1;

  f32x4 acc[4][4] = {};

  const unsigned short* Ag = Abf + (size_t)brow * 128 * KD;
  const unsigned short* Bg = Vbf + (size_t)bcol * 128 * KD;
  const int f0 = wv * 128 + lane;   // 16B-chunk index; f0,f1 cover [0,512)
  const int f1 = f0 + 64;
  const int r0 = lane & 15, kc = (lane >> 4) * 8;

  for (int kt = 0; kt < KD; kt += 32) {
    __syncthreads();
    GLD16(Ag + ((f0 >> 2) * KD + kt + (f0 & 3) * 8), &As[f0 * 8]);
    GLD16(Bg + ((f0 >> 2) * KD + kt + (f0 & 3) * 8), &Bs[f0 * 8]);
    GLD16(Ag + ((f1 >> 2) * KD + kt + (f1 & 3) * 8), &As[f1 * 8]);
    GLD16(Bg + ((f1 >> 2) * KD + kt + (f1 & 3) * 8), &Bs[f1 * 8]);
    __syncthreads();
    short8 a[4], b[4];
    #pragma unroll
    for (int m = 0; m < 4; ++m)
      a[m] = *(const short8*)&As[(wr * 64 + m * 16 + r0) * 32 + kc];
    #pragma unroll
    for (int n = 0; n < 4; ++n)
      b[n] = *(const short8*)&Bs[(wc * 64 + n * 16 + r0) * 32 + kc];
    #pragma unroll
    for (int m = 0; m < 4; ++m)
      #pragma unroll
      for (int n = 0; n < 4; ++n)
        acc[m][n] = __builtin_amdgcn_mfma_f32_16x16x32_bf16(b[n], a[m], acc[m][n], 0, 0, 0);
  }

  // Epilogue: float4 R reads matching the swapped acc layout.
  float lsum = 0.f;
  const int row0 = brow * 128 + wr * 64 + (lane & 15);
  const size_t col0 = (size_t)bcol * 128 + wc * 64 + (lane >> 4) * 4;
  #pragma unroll
  for (int m = 0; m < 4; ++m) {
    const float* rp = R + (size_t)(row0 + m * 16) * N_I + col0;
    #pragma unroll
    for (int n = 0; n < 4; ++n) {
      float4 rv = *(const float4*)&rp[n * 16];
      if (rv.x != 0.f) { float d = rv.x - acc[m][n][0]; lsum += d * d; }
      if (rv.y != 0.f) { float d = rv.y - acc[m][n][1]; lsum += d * d; }
      if (rv.z != 0.f) { float d = rv.z - acc[m][n][2]; lsum += d * d; }
      if (rv.w != 0.f) { float d = rv.w - acc[m][n][3]; lsum += d * d; }
    }
  }

  // block reduce, reusing As as scratch; plain store to this block's slot.
  #pragma unroll
  for (int off = 32; off > 0; off >>= 1) lsum += __shfl_down(lsum, off, 64);
  float* red = (float*)As;
  __syncthreads();
  if (lane == 0) red[wv] = lsum;
  __syncthreads();
  if (tid == 0) ws[blockIdx.y * 64 + blockIdx.x] = red[0] + red[1] + red[2] + red[3];
}

// Reduce all slots: out = err/2 + 0.1/2 * regsum.
__global__ __launch_bounds__(256) void finalize_kernel(
    const float* __restrict__ ws, float* __restrict__ out)
{
  __shared__ float sh[256];
  const int tid = threadIdx.x;
  float e = 0.f, r = 0.f;
  for (int i = tid; i < ERR_SLOTS; i += 256) e += ws[i];
  for (int i = REGA_BASE + tid; i < SLOTS_END; i += 256) r += ws[i];
  sh[tid] = 0.5f * e + 0.05f * r;
  __syncthreads();
  #pragma unroll
  for (int s = 128; s > 0; s >>= 1) {
    if (tid < s) sh[tid] += sh[tid + s];
    __syncthreads();
  }
  if (tid == 0) out[0] = sh[0];
}

extern "C" void kernel_launch(void* const* d_in, const int* in_sizes, int n_in,
                              void* d_out, int out_size, void* d_ws, size_t ws_size,
                              hipStream_t stream) {
  const float* R = (const float*)d_in[0];
  const float* U = (const float*)d_in[1];
  const float* V = (const float*)d_in[2];
  // d_in[3]=alpha, d_in[4]=Y, d_in[6]=Q: dead w.r.t. the returned value.
  const float* P = (const float*)d_in[5];

  float* ws = (float*)d_ws;                                      // 6656 slots
  unsigned short* Abf = (unsigned short*)((char*)d_ws + 32768);  // 4 MiB
  unsigned short* Vbf = Abf + (size_t)N_U * KD;                  // 4 MiB
  float* out = (float*)d_out;

  pack_a_kernel<<<dim3(N_U / 64, KD / 64), 256, 0, stream>>>(U, P, Abf, ws);
  pack_v_kernel<<<dim3((N_I * KD) / (256 * 4)), 256, 0, stream>>>(V, Vbf, ws);
  gemm_loss_kernel<<<dim3(64, 64), 256, 0, stream>>>(R, Abf, Vbf, ws);
  finalize_kernel<<<1, 256, 0, stream>>>(ws, out);
}